// Round 1
// baseline (183.152 us; speedup 1.0000x reference)
//
#include <hip/hip_runtime.h>
#include <hip/hip_bf16.h>
#include <stdint.h>

// GraphConvolution: out = relu(x@W1^T + b1 + aggr@W2^T + b2), aggr = sum of 16 neighbor rows.
// Strategy: fold into single bf16 GEMM  [x|aggr](100000x256) @ [W1;W2]^T(256x128) + (b1+b2), relu.

#define N_NODES 100000
#define DEG 16
#define KTOT 256
#define M_PAD 100096  // 782 * 128 (GEMM-tile padded; pad rows read poison, outputs discarded)

typedef __attribute__((ext_vector_type(8))) short short8;
typedef __attribute__((ext_vector_type(4))) float floatx4;

static __device__ __forceinline__ unsigned short f2bf(float f) {
  union { float f; uint32_t u; } v; v.f = f;
  uint32_t u = v.u;
  return (unsigned short)((u + 0x7fffu + ((u >> 16) & 1u)) >> 16);  // RNE
}
static __device__ __forceinline__ float bf2f(uint32_t bits16) {
  union { uint32_t u; float f; } v; v.u = bits16 << 16; return v.f;
}

// ---- kernel 1: Wcat bf16 [128 out][256 k] (row o = [W1[o,:], W2[o,:]]) + bias = b1+b2 ----
__global__ __launch_bounds__(256) void k_prep(const float* __restrict__ W1, const float* __restrict__ b1,
                                              const float* __restrict__ W2, const float* __restrict__ b2,
                                              unsigned short* __restrict__ Bt, float* __restrict__ bias) {
  int t = blockIdx.x * 256 + threadIdx.x;  // 0..32767
  int o = t >> 8, k = t & 255;
  float v = (k < 128) ? W1[o * 128 + k] : W2[o * 128 + (k - 128)];
  Bt[t] = f2bf(v);
  if (t < 128) bias[t] = b1[t] + b2[t];
}

// ---- kernel 2: x fp32 -> bf16 into combined A[:, 0:128] ----
__global__ __launch_bounds__(256) void k_convert(const float* __restrict__ x,
                                                 unsigned short* __restrict__ A) {
  int t = blockIdx.x * 256 + threadIdx.x;  // float4 index, N*32 total
  if (t >= N_NODES * 32) return;
  int n = t >> 5, c4 = t & 31;
  float4 v = *(const float4*)(x + (size_t)n * 128 + (size_t)c4 * 4);
  ushort4 o;
  o.x = f2bf(v.x); o.y = f2bf(v.y); o.z = f2bf(v.z); o.w = f2bf(v.w);
  *(ushort4*)(A + (size_t)n * 256 + (size_t)c4 * 4) = o;
}

// ---- kernel 3: gather-sum 16 neighbor bf16 rows (fp32 accum) into A[:, 128:256] ----
__global__ __launch_bounds__(256) void k_aggr(const int* __restrict__ nbrs,
                                              unsigned short* __restrict__ A) {
  int gid = blockIdx.x * 4 + (threadIdx.x >> 6);  // one wave per node, exact at 25000 blocks
  int lane = threadIdx.x & 63;
  int myidx = nbrs[(size_t)gid * DEG + (lane & 15)];  // lanes 0..15 hold the 16 indices
  float a0 = 0.f, a1 = 0.f;
#pragma unroll
  for (int j = 0; j < DEG; ++j) {
    int nb = __shfl(myidx, j);
    uint32_t pv = *(const uint32_t*)(A + (size_t)nb * 256 + (size_t)lane * 2);  // 2 bf16, 256B/row coalesced
    a0 += bf2f(pv & 0xffffu);
    a1 += bf2f(pv >> 16);
  }
  uint32_t w = (uint32_t)f2bf(a0) | ((uint32_t)f2bf(a1) << 16);
  *(uint32_t*)(A + (size_t)gid * 256 + 128 + (size_t)lane * 2) = w;
}

// ---- kernel 4: GEMM [M_PAD x 256] x [256 x 128] bf16 MFMA, fused bias+relu, fp32 out ----
// 128x128 tile / block, 4 waves (2x2 of 64x64), BK=64, global_load_lds(16B) staging.
// LDS XOR slot-swizzle (phys_slot = k_slot ^ (row&7)) applied by pre-swizzling the GLOBAL
// source address (linear LDS dest, per m104/m201 pattern); reads XOR the same involution.
__global__ __launch_bounds__(256) void k_gemm(const unsigned short* __restrict__ A,
                                              const unsigned short* __restrict__ Bt,
                                              const float* __restrict__ bias,
                                              float* __restrict__ out) {
  __shared__ unsigned short lds[16384];  // As bytes [0,16384), Bs bytes [16384,32768)
  const int tid = threadIdx.x;
  const int lane = tid & 63;
  const int w = tid >> 6;
  const int wm = w >> 1, wn = w & 1;
  const size_t tile_m = (size_t)blockIdx.x * 128;

  floatx4 acc[4][4];
#pragma unroll
  for (int i = 0; i < 4; ++i)
#pragma unroll
    for (int j = 0; j < 4; ++j) acc[i][j] = (floatx4){0.f, 0.f, 0.f, 0.f};

  const int l8 = lane >> 3;              // row-within-8 of the staged chunk
  const int slot_sw = (lane & 7) ^ l8;   // pre-swizzled global k-slot (16B slots)
  const unsigned short* Ag = A + tile_m * 256;

  for (int kt = 0; kt < 4; ++kt) {
    __syncthreads();  // protect LDS from overwrite
#pragma unroll
    for (int p = 0; p < 4; ++p) {  // stage A: 128 rows x 64 k (16KB)
      int row = p * 32 + w * 8 + l8;
      const unsigned short* g = Ag + (size_t)row * 256 + kt * 64 + slot_sw * 8;
      __builtin_amdgcn_global_load_lds((const __attribute__((address_space(1))) uint32_t*)g,
                                       (__attribute__((address_space(3))) uint32_t*)&lds[(p * 4 + w) * 512],
                                       16, 0, 0);
    }
#pragma unroll
    for (int p = 0; p < 4; ++p) {  // stage B^T: 128 outs x 64 k (16KB)
      int row = p * 32 + w * 8 + l8;
      const unsigned short* g = Bt + (size_t)row * 256 + kt * 64 + slot_sw * 8;
      __builtin_amdgcn_global_load_lds((const __attribute__((address_space(1))) uint32_t*)g,
                                       (__attribute__((address_space(3))) uint32_t*)&lds[8192 + (p * 4 + w) * 512],
                                       16, 0, 0);
    }
    __syncthreads();  // compiler drains vmcnt(0) before barrier -> data ready

#pragma unroll
    for (int ks = 0; ks < 2; ++ks) {
      short8 a[4], b[4];
      const int kb = ks * 64 + (lane >> 4) * 16;   // byte offset of this lane's 8 k-elems
      const int swz = (lane & 7) << 4;             // row&7 == lane&7 for all frag rows
#pragma unroll
      for (int mi = 0; mi < 4; ++mi) {
        int row = wm * 64 + mi * 16 + (lane & 15);
        a[mi] = *(const short8*)((const char*)lds + row * 128 + (kb ^ swz));
      }
#pragma unroll
      for (int ni = 0; ni < 4; ++ni) {
        int row = wn * 64 + ni * 16 + (lane & 15);
        b[ni] = *(const short8*)((const char*)lds + 16384 + row * 128 + (kb ^ swz));
      }
#pragma unroll
      for (int mi = 0; mi < 4; ++mi)
#pragma unroll
        for (int ni = 0; ni < 4; ++ni)
          acc[mi][ni] = __builtin_amdgcn_mfma_f32_16x16x32_bf16(a[mi], b[ni], acc[mi][ni], 0, 0, 0);
    }
  }

  // epilogue: C/D layout col=lane&15, row=(lane>>4)*4+reg (m89-verified)
  float bcol[4];
#pragma unroll
  for (int ni = 0; ni < 4; ++ni) bcol[ni] = bias[wn * 64 + ni * 16 + (lane & 15)];
  const int r0 = (lane >> 4) * 4;
#pragma unroll
  for (int mi = 0; mi < 4; ++mi) {
    size_t mbase = tile_m + wm * 64 + mi * 16 + r0;
#pragma unroll
    for (int r = 0; r < 4; ++r) {
      size_t mrow = mbase + r;
      if (mrow < N_NODES) {
        float* orow = out + mrow * 128 + wn * 64 + (lane & 15);
#pragma unroll
        for (int ni = 0; ni < 4; ++ni) {
          float vv = acc[mi][ni][r] + bcol[ni];
          orow[ni * 16] = vv > 0.f ? vv : 0.f;
        }
      }
    }
  }
}

extern "C" void kernel_launch(void* const* d_in, const int* in_sizes, int n_in,
                              void* d_out, int out_size, void* d_ws, size_t ws_size,
                              hipStream_t stream) {
  const int* nbrs  = (const int*)d_in[0];
  const float* x   = (const float*)d_in[1];
  const float* W1  = (const float*)d_in[2];
  const float* b1  = (const float*)d_in[3];
  const float* W2  = (const float*)d_in[4];
  const float* b2  = (const float*)d_in[5];
  float* out = (float*)d_out;

  // workspace layout: A bf16 [M_PAD][256] | Bt bf16 [128][256] | bias f32 [128]
  unsigned short* A  = (unsigned short*)d_ws;
  unsigned short* Bt = A + (size_t)M_PAD * 256;
  float* bias = (float*)(Bt + 128 * 256);

  k_prep<<<128, 256, 0, stream>>>(W1, b1, W2, b2, Bt, bias);
  k_convert<<<12500, 256, 0, stream>>>(x, A);
  k_aggr<<<25000, 256, 0, stream>>>(nbrs, A);
  k_gemm<<<782, 256, 0, stream>>>(A, Bt, bias, out);
}

// Round 3
// 177.582 us; speedup vs baseline: 1.0314x; 1.0314x over previous
//
#include <hip/hip_runtime.h>
#include <stdint.h>

// GraphConvolution: out = relu(x@W1^T + b1 + aggr@W2^T + b2), aggr = sum of 16 neighbor rows.
// Folded into one bf16 GEMM: [x|aggr](100000x256) @ [W1;W2]^T(256x128) + (b1+b2), relu.
// R1: pipelined GEMM (depth-3, counted vmcnt, raw barriers), prep merged into convert,
//     dwordx2 gather in k_aggr.
// R2: resubmit (R1 bench was lost to GPUAcquisitionTimeout — no data).

#define N_NODES 100000
#define DEG 16
#define M_PAD 100096  // 782 * 128

typedef __attribute__((ext_vector_type(8))) short short8;
typedef __attribute__((ext_vector_type(4))) float floatx4;

static __device__ __forceinline__ unsigned short f2bf(float f) {
  union { float f; uint32_t u; } v; v.f = f;
  uint32_t u = v.u;
  return (unsigned short)((u + 0x7fffu + ((u >> 16) & 1u)) >> 16);  // RNE
}
static __device__ __forceinline__ float bf2f(uint32_t bits16) {
  union { uint32_t u; float f; } v; v.u = bits16 << 16; return v.f;
}

// ---- kernel 1: x fp32 -> bf16 into A[:,0:128]  +  W/bias prep (merged) ----
__global__ __launch_bounds__(256) void k_convert(const float* __restrict__ x,
                                                 unsigned short* __restrict__ A,
                                                 const float* __restrict__ W1, const float* __restrict__ b1,
                                                 const float* __restrict__ W2, const float* __restrict__ b2,
                                                 unsigned short* __restrict__ Bt, float* __restrict__ bias) {
  int b = blockIdx.x;
  if (b < 12500) {                      // convert: 12500*256 threads == N*32 float4 chunks exactly
    int t = b * 256 + threadIdx.x;
    int n = t >> 5, c4 = t & 31;
    float4 v = *(const float4*)(x + (size_t)n * 128 + (size_t)c4 * 4);
    ushort4 o;
    o.x = f2bf(v.x); o.y = f2bf(v.y); o.z = f2bf(v.z); o.w = f2bf(v.w);
    *(ushort4*)(A + (size_t)n * 256 + (size_t)c4 * 4) = o;
  } else {                              // prep: Bt row o = [W1[o,:], W2[o,:]] bf16; bias = b1+b2
    int t = (b - 12500) * 256 + threadIdx.x;  // 0..32767
    int o = t >> 8, k = t & 255;
    float v = (k < 128) ? W1[o * 128 + k] : W2[o * 128 + (k - 128)];
    Bt[t] = f2bf(v);
    if (t < 128) bias[t] = b1[t] + b2[t];
  }
}

// ---- kernel 2: gather-sum 16 neighbor bf16 rows (fp32 accum) into A[:,128:256] ----
// one wave/node; dwordx2 loads: 2 rows per instruction, 8 loads/node.
__global__ __launch_bounds__(256) void k_aggr(const int* __restrict__ nbrs,
                                              unsigned short* __restrict__ A) {
  int gid = blockIdx.x * 4 + (threadIdx.x >> 6);  // exact at 25000 blocks
  int lane = threadIdx.x & 63;
  int myidx = nbrs[(size_t)gid * DEG + (lane & 15)];
  int half = lane >> 5;   // which of the 2 rows this instr
  int c = lane & 31;      // 4-col group: cols 4c..4c+3
  float a0 = 0.f, a1 = 0.f, a2 = 0.f, a3 = 0.f;
#pragma unroll
  for (int i = 0; i < 8; ++i) {
    int nb = __shfl(myidx, 2 * i + half);
    uint2 pv = *(const uint2*)(A + (size_t)nb * 256 + (size_t)c * 4);  // 8B/lane, 2x256B segments
    a0 += bf2f(pv.x & 0xffffu); a1 += bf2f(pv.x >> 16);
    a2 += bf2f(pv.y & 0xffffu); a3 += bf2f(pv.y >> 16);
  }
  a0 += __shfl_xor(a0, 32); a1 += __shfl_xor(a1, 32);
  a2 += __shfl_xor(a2, 32); a3 += __shfl_xor(a3, 32);
  if (lane < 32) {
    uint2 w;
    w.x = (uint32_t)f2bf(a0) | ((uint32_t)f2bf(a1) << 16);
    w.y = (uint32_t)f2bf(a2) | ((uint32_t)f2bf(a3) << 16);
    *(uint2*)(A + (size_t)gid * 256 + 128 + (size_t)c * 4) = w;
  }
}

// ---- kernel 3: GEMM [M_PAD x 256] x [256 x 128] bf16 MFMA, fused bias+relu, fp32 out ----
// 128x128 tile/block, 4 waves (2x2 of 64x64). BK=32 stages, depth-3 pipeline:
// 3 LDS buffers x 16KB (A 8KB + B 8KB each), raw s_barrier + counted vmcnt (never 0 mid-loop).
// Rows are 64B in LDS; XOR swizzle slot^(row&3) applied via pre-swizzled GLOBAL source
// (linear LDS dest, per m104/m201), reads XOR the same involution.
#define VMW(n) asm volatile("s_waitcnt vmcnt(" #n ")" ::: "memory")
#define BAR()  { asm volatile("" ::: "memory"); __builtin_amdgcn_s_barrier(); asm volatile("" ::: "memory"); }

__global__ __launch_bounds__(256, 3) void k_gemm(const unsigned short* __restrict__ A,
                                                 const unsigned short* __restrict__ Bt,
                                                 const float* __restrict__ bias,
                                                 float* __restrict__ out) {
  __shared__ unsigned short lds[24576];  // 3 x 16KB
  const int tid = threadIdx.x;
  const int lane = tid & 63;
  const int w = tid >> 6;
  const int wm = w >> 1, wn = w & 1;
  const size_t tile_m = (size_t)blockIdx.x * 128;

  // bias FIRST: its 4 vmem loads are in the vmcnt ledger before staging starts
  float bcol[4];
#pragma unroll
  for (int ni = 0; ni < 4; ++ni) bcol[ni] = bias[wn * 64 + ni * 16 + (lane & 15)];

  const int l4 = lane >> 2;                         // row-within-16 of staged chunk
  const int sw = ((lane & 3) ^ (l4 & 3)) * 16;      // pre-swizzled 16B slot (byte offset)
  const char* Agb = (const char*)A + tile_m * 512;  // 512B rows
  const char* Bgb = (const char*)Bt;
  char* ldsb = (char*)lds;

  floatx4 acc[4][4];
#pragma unroll
  for (int i = 0; i < 4; ++i)
#pragma unroll
    for (int j = 0; j < 4; ++j) acc[i][j] = (floatx4){0.f, 0.f, 0.f, 0.f};

  auto STAGE = [&](int t) {  // 4 gload_lds per wave per stage
    char* base = ldsb + (t % 3) * 16384;
    int ko = t * 64;  // k-window byte offset within 512B row
#pragma unroll
    for (int i = 0; i < 2; ++i) {
      int r16 = w * 32 + i * 16;
      const char* gA = Agb + (size_t)(r16 + l4) * 512 + ko + sw;
      __builtin_amdgcn_global_load_lds((const __attribute__((address_space(1))) uint32_t*)gA,
                                       (__attribute__((address_space(3))) uint32_t*)(base + r16 * 64),
                                       16, 0, 0);
      const char* gB = Bgb + (size_t)(r16 + l4) * 512 + ko + sw;
      __builtin_amdgcn_global_load_lds((const __attribute__((address_space(1))) uint32_t*)gB,
                                       (__attribute__((address_space(3))) uint32_t*)(base + 8192 + r16 * 64),
                                       16, 0, 0);
    }
  };

  auto COMPUTE = [&](int t) {  // 16 MFMA per stage (K=32 per frag)
    const char* base = ldsb + (t % 3) * 16384;
    const int kb = (lane >> 4) * 16;
    short8 a[4], b[4];
#pragma unroll
    for (int mi = 0; mi < 4; ++mi) {
      int row = wm * 64 + mi * 16 + (lane & 15);
      a[mi] = *(const short8*)(base + row * 64 + (kb ^ ((row & 3) << 4)));
    }
#pragma unroll
    for (int ni = 0; ni < 4; ++ni) {
      int row = wn * 64 + ni * 16 + (lane & 15);
      b[ni] = *(const short8*)(base + 8192 + row * 64 + (kb ^ ((row & 3) << 4)));
    }
#pragma unroll
    for (int mi = 0; mi < 4; ++mi)
#pragma unroll
      for (int ni = 0; ni < 4; ++ni)
        acc[mi][ni] = __builtin_amdgcn_mfma_f32_16x16x32_bf16(a[mi], b[ni], acc[mi][ni], 0, 0, 0);
  };

  // prologue: 3 stages in flight (ledger: bias 4 + 12 stage loads)
  STAGE(0); STAGE(1); STAGE(2);
  // steady state: VMW(8) == "stage t landed" (bias + S_t drained, 2 stages in flight)
  VMW(8); BAR(); COMPUTE(0); BAR(); STAGE(3);
  VMW(8); BAR(); COMPUTE(1); BAR(); STAGE(4);
  VMW(8); BAR(); COMPUTE(2); BAR(); STAGE(5);
  VMW(8); BAR(); COMPUTE(3); BAR(); STAGE(6);
  VMW(8); BAR(); COMPUTE(4); BAR(); STAGE(7);
  VMW(8); BAR(); COMPUTE(5); BAR();
  VMW(4); BAR(); COMPUTE(6); BAR();
  VMW(0); BAR(); COMPUTE(7);

  // epilogue: C/D layout col=lane&15, row=(lane>>4)*4+reg (m89-verified)
  const int r0 = (lane >> 4) * 4;
#pragma unroll
  for (int mi = 0; mi < 4; ++mi) {
    size_t mbase = tile_m + wm * 64 + mi * 16 + r0;
#pragma unroll
    for (int r = 0; r < 4; ++r) {
      size_t mrow = mbase + r;
      if (mrow < N_NODES) {
        float* orow = out + mrow * 128 + wn * 64 + (lane & 15);
#pragma unroll
        for (int ni = 0; ni < 4; ++ni) {
          float vv = acc[mi][ni][r] + bcol[ni];
          orow[ni * 16] = vv > 0.f ? vv : 0.f;
        }
      }
    }
  }
}

extern "C" void kernel_launch(void* const* d_in, const int* in_sizes, int n_in,
                              void* d_out, int out_size, void* d_ws, size_t ws_size,
                              hipStream_t stream) {
  const int* nbrs  = (const int*)d_in[0];
  const float* x   = (const float*)d_in[1];
  const float* W1  = (const float*)d_in[2];
  const float* b1  = (const float*)d_in[3];
  const float* W2  = (const float*)d_in[4];
  const float* b2  = (const float*)d_in[5];
  float* out = (float*)d_out;

  // ws layout: A bf16 [M_PAD][256] | Bt bf16 [128][256] | bias f32 [128]
  unsigned short* A  = (unsigned short*)d_ws;
  unsigned short* Bt = A + (size_t)M_PAD * 256;
  float* bias = (float*)(Bt + 128 * 256);

  k_convert<<<12628, 256, 0, stream>>>(x, A, W1, b1, W2, b2, Bt, bias);
  k_aggr<<<25000, 256, 0, stream>>>(nbrs, A);
  k_gemm<<<782, 256, 0, stream>>>(A, Bt, bias, out);
}